// Round 11
// baseline (154.474 us; speedup 1.0000x reference)
//
#include <hip/hip_runtime.h>
#include <hip/hip_fp16.h>
#include <math.h>

// Problem constants: B=4, M=4096, D=64, W=128
constexpr int B = 4;
constexpr int M = 4096;
constexpr int D = 64;
constexpr int W = 128;
constexpr int NELEM = B * M * D;

constexpr int TT  = 64;        // k-rows per tile
constexpr int NTT = M / TT;    // 64 tiles
constexpr int RB  = 64;        // m-rows per block

typedef _Float16 h2_t __attribute__((ext_vector_type(2)));
typedef int      i4_t __attribute__((ext_vector_type(4)));

typedef __attribute__((address_space(1))) const void* gptr_t;
typedef __attribute__((address_space(3))) void*       sptr_t;

// ---- pass 1: fp32 -> fp16 of k AND v ----
__global__ __launch_bounds__(256) void cvt_f32_f16_2(
    const float4* __restrict__ k, const float4* __restrict__ v,
    __half2* __restrict__ kh, __half2* __restrict__ vh, int n4) {
    int i = blockIdx.x * 256 + threadIdx.x;
    const float4* src;
    __half2* dst;
    if (i < n4) { src = k; dst = kh; }
    else        { src = v; dst = vh; i -= n4; if (i >= n4) return; }
    float4 f = src[i];
    dst[2 * i]     = __floats2half2_rn(f.x, f.y);
    dst[2 * i + 1] = __floats2half2_rn(f.z, f.w);
}

// ---- pass 2: per-row tile-sort (by idx>>6, TT=64) of the 128 indices,
// written TRANSPOSED: idx2t[pos * M + m]. Order within a tile arbitrary
// (softmax+PV permutation-invariant); idx shared across batches.
__global__ __launch_bounds__(256) void bucket_idx_t(
    const int* __restrict__ idx, unsigned short* __restrict__ idx2t) {
    const int m    = blockIdx.x * 4 + (threadIdx.x >> 6);
    const int lane = threadIdx.x & 63;
    const int* row = idx + (size_t)m * W;
    const int j0 = row[lane], j1 = row[lane + 64];
    const int b0 = j0 >> 6,   b1 = j1 >> 6;
    const unsigned long long lt = (1ULL << lane) - 1ULL;
    int base = 0;
    for (int t = 0; t < NTT; ++t) {
        const unsigned long long q0 = __ballot(b0 == t);
        const unsigned long long q1 = __ballot(b1 == t);
        const int c0 = __popcll(q0);
        if (b0 == t)
            idx2t[(size_t)(base + __popcll(q0 & lt)) * M + m] = (unsigned short)j0;
        if (b1 == t)
            idx2t[(size_t)(base + c0 + __popcll(q1 & lt)) * M + m] = (unsigned short)j1;
        base += c0 + __popcll(q1);
    }
}

// all-DPP 8-lane reduction: xor1/xor2 via quad_perm, cross-quad fold via
// row_half_mirror (0x141). All 64 lanes always active (loop body is
// branch-free predicated), so DPP sources are never exec-masked.
template <int CTRL>
__device__ __forceinline__ float dpp_add(float x) {
    const int yi = __builtin_amdgcn_update_dpp(
        0, __builtin_bit_cast(int, x), CTRL, 0xF, 0xF, true);
    return x + __builtin_bit_cast(float, yi);
}

// ---- main kernel: dense-streamed K/V ring + sorted-window consumption,
// ENTRY-PAIR passes at 2 blocks/CU. R10 post-mortem: 74 µs, VALUBusy 33%,
// Occupancy 19.5% — latency-bound at 2 waves/SIMD (112 KB LDS) with a
// serial per-entry chain. Changes:
//  * TT=64, 3-slot ring (48 KB) + idx (16 KB) = 64 KB LDS -> 2 blocks/CU
//    = 4 waves/SIMD (launch_bounds(512,4)); other block hides barriers.
//  * pair processing: 2 entries per pass per group; both K/V b128 reads
//    issued together (2x MLP); 2-entry lookahead regs (cur,nx1) + 2
//    prefetched idx reads per pass (f2,f3) keep the stream recurrence off
//    the critical path.
//  * fully predicated: no divergent if(adv) — disabled entries contribute
//    pw = exp(-3e30 - mrun) = 0. Loop body is uniform, branch-free.
//  * defer-max on the pair max; rescale branch is group-uniform and rare.
//  * cross-wave staging rule: own vmcnt(0) BEFORE bottom barrier.
__global__ __launch_bounds__(512, 4) void sparse_attn_p2(
    const float* __restrict__ q,
    const __half* __restrict__ kh,
    const __half* __restrict__ vh,
    const unsigned short* __restrict__ idx2t,
    float* __restrict__ out)
{
    const int blk  = blockIdx.x;
    const int b    = blk & 3;              // XCD pinning: 2 XCDs per batch
    const int mc   = blk >> 2;             // 0..63
    const int tid  = threadIdx.x;
    const int wave = tid >> 6;             // 0..7
    const int lane = tid & 63;
    const int g    = lane >> 3;            // group (row) within wave: 0..7
    const int c    = lane & 7;             // dim-chunk: dims [c*8, c*8+8)
    const int rl   = wave * 8 + g;         // 0..63 local row
    const int m    = mc * RB + rl;

    __shared__ i4_t ring_k[3 * TT * 8];                        // 24 KB
    __shared__ i4_t ring_v[3 * TT * 8];                        // 24 KB
    __shared__ __align__(16) unsigned short idx2_s[W][RB];     // 16 KB

    const char* kb = (const char*)(kh + (size_t)b * M * D);
    const char* vb = (const char*)(vh + (size_t)b * M * D);

    // staging: tile = 8 KB K + 8 KB V; per wave 1 KB K + 1 KB V (2 gl_lds).
    auto stage = [&](int u) {
        const int s = u % 3;
        const char* ks = kb + (size_t)u * 8192 + wave * 1024 + lane * 16;
        const char* vs = vb + (size_t)u * 8192 + wave * 1024 + lane * 16;
        char* kd = (char*)ring_k + s * 8192 + wave * 1024;
        char* vd = (char*)ring_v + s * 8192 + wave * 1024;
        __builtin_amdgcn_global_load_lds((gptr_t)ks, (sptr_t)kd, 16, 0, 0);
        __builtin_amdgcn_global_load_lds((gptr_t)vs, (sptr_t)vd, 16, 0, 0);
    };

    // idx staging: [pos][64 rows] u16; per wave 16 pos-rows = 2 gl_lds.
    {
        const int p0 = wave * 16;
        #pragma unroll
        for (int i = 0; i < 2; ++i) {
            const int pr = p0 + i * 8 + (lane >> 3);
            const size_t so = ((size_t)pr * M + (size_t)mc * RB + (lane & 7) * 8) * 2;
            __builtin_amdgcn_global_load_lds((gptr_t)((const char*)idx2t + so),
                (sptr_t)&idx2_s[p0 + i * 8][0], 16, 0, 0);
        }
    }
    stage(0);
    stage(1);

    // q fragment: dims [c*8, c*8+8) as 4x half2 for fdot2
    const float* qrow = q + ((size_t)b * M + m) * D + c * 8;
    const float4 qa = ((const float4*)qrow)[0];
    const float4 qc = ((const float4*)qrow)[1];
    h2_t qh[4];
    qh[0] = (h2_t){(_Float16)qa.x, (_Float16)qa.y};
    qh[1] = (h2_t){(_Float16)qa.z, (_Float16)qa.w};
    qh[2] = (h2_t){(_Float16)qc.x, (_Float16)qc.y};
    qh[3] = (h2_t){(_Float16)qc.z, (_Float16)qc.w};

    asm volatile("s_waitcnt vmcnt(0)" ::: "memory");
    __syncthreads();                       // idx + tiles 0,1 resident (all waves)

    float acc[8] = {0, 0, 0, 0, 0, 0, 0, 0};
    float mrun = -1e30f;
    float l = 0.f;

    int pos = 0;
    int cur = idx2_s[0][rl];               // group-uniform broadcasts
    int nx1 = idx2_s[1][rl];

    for (int t = 0; t < NTT; ++t) {
        if (t + 2 < NTT) stage(t + 2);     // lands during consume(t)

        const int s0 = (t % 3) * (TT * 8);         // i4 index of slot t
        const int s1 = ((t + 1) % 3) * (TT * 8);   // slot t+1

        // consume: forced tile t, opportunistic t+1; 2 entries per pass.
        // Guard converts any unmodeled non-advance into a wrong answer
        // instead of a hang (legal runs never hit it).
        for (int guard = 0; guard < W + 2 && __any((cur >> 6) <= t); ++guard) {
            const bool a0 = ((cur >> 6) <= t + 1);
            const bool a1 = a0 && ((nx1 >> 6) <= t + 1);   // sorted stream
            // prefetch stream lookahead (latency hidden under compute)
            const int pp2 = pos + 2, pp3 = pos + 3;
            const int f2r = idx2_s[(pp2 < W) ? pp2 : 0][rl];
            const int f3r = idx2_s[(pp3 < W) ? pp3 : 0][rl];
            const int f2 = (pp2 < W) ? f2r : 0x7FFF;
            const int f3 = (pp3 < W) ? f3r : 0x7FFF;
            // K/V reads for both entries; when predicated-off the address
            // is garbage-but-in-bounds (slot s1, row cur&63).
            const int ko0 = (((cur >> 6) > t) ? s1 : s0) + (cur & (TT - 1)) * 8 + c;
            const int ko1 = (((nx1 >> 6) > t) ? s1 : s0) + (nx1 & (TT - 1)) * 8 + c;
            union { i4_t v; h2_t h[4]; } uk0, uk1, uv0, uv1;
            uk0.v = ring_k[ko0];
            uk1.v = ring_k[ko1];
            uv0.v = ring_v[ko0];
            uv1.v = ring_v[ko1];
            float p0 = __builtin_amdgcn_fdot2(uk0.h[0], qh[0], 0.f, false);
            p0 = __builtin_amdgcn_fdot2(uk0.h[1], qh[1], p0, false);
            p0 = __builtin_amdgcn_fdot2(uk0.h[2], qh[2], p0, false);
            p0 = __builtin_amdgcn_fdot2(uk0.h[3], qh[3], p0, false);
            float p1 = __builtin_amdgcn_fdot2(uk1.h[0], qh[0], 0.f, false);
            p1 = __builtin_amdgcn_fdot2(uk1.h[1], qh[1], p1, false);
            p1 = __builtin_amdgcn_fdot2(uk1.h[2], qh[2], p1, false);
            p1 = __builtin_amdgcn_fdot2(uk1.h[3], qh[3], p1, false);
            p0 = dpp_add<0xB1>(p0);  p1 = dpp_add<0xB1>(p1);   // xor1
            p0 = dpp_add<0x4E>(p0);  p1 = dpp_add<0x4E>(p1);   // xor2
            p0 = dpp_add<0x141>(p0); p1 = dpp_add<0x141>(p1);  // cross-quad
            const float e0 = a0 ? p0 : -3e30f;
            const float e1 = a1 ? p1 : -3e30f;
            const float pm = fmaxf(e0, e1);
            const float dd = pm - mrun;
            if (dd > 8.0f) {               // defer-max: rare, group-uniform
                const float sc_ = __expf(-dd);
                l *= sc_;
                #pragma unroll
                for (int i2 = 0; i2 < 8; ++i2) acc[i2] *= sc_;
                mrun = pm;
            }
            const float pw0 = __expf(e0 - mrun);   // 0 when predicated off
            const float pw1 = __expf(e1 - mrun);
            l += pw0 + pw1;
            #pragma unroll
            for (int j = 0; j < 4; ++j) {
                acc[2 * j]     += pw0 * (float)uv0.h[j][0] + pw1 * (float)uv1.h[j][0];
                acc[2 * j + 1] += pw0 * (float)uv0.h[j][1] + pw1 * (float)uv1.h[j][1];
            }
            pos += (int)a0 + (int)a1;
            const int ncur = a1 ? f2 : (a0 ? nx1 : cur);
            const int nnx1 = a1 ? f3 : (a0 ? f2 : nx1);
            cur = ncur;
            nx1 = nnx1;
        }

        if (t + 1 < NTT) {
            // own stage(t+2) done BEFORE barrier => after barrier ALL
            // waves' t+2 loads complete (cross-wave correctness key).
            asm volatile("s_waitcnt vmcnt(0)" ::: "memory");
            __builtin_amdgcn_s_barrier();
            asm volatile("" ::: "memory");
        }
    }

    const float inv = 1.0f / l;
    float* orow = out + ((size_t)b * M + m) * D + c * 8;
    ((float4*)orow)[0] = make_float4(acc[0] * inv, acc[1] * inv,
                                     acc[2] * inv, acc[3] * inv);
    ((float4*)orow)[1] = make_float4(acc[4] * inv, acc[5] * inv,
                                     acc[6] * inv, acc[7] * inv);
}

// ---- fallback fp32 kernel if workspace too small ----
__global__ __launch_bounds__(128) void sparse_attn_f32(
    const float* __restrict__ q,
    const float* __restrict__ k,
    const float* __restrict__ v,
    const int*   __restrict__ idx,
    float*       __restrict__ out)
{
    const int blk = blockIdx.x;
    const int b = blk & 3;
    const int m = blk >> 2;
    const int t = threadIdx.x;
    const int lane = t & 63;
    const int wave = t >> 6;
    const int ci = lane & 15;
    const int r  = lane >> 4;

    __shared__ int   idx_s[W];
    __shared__ float sc_s[W];
    __shared__ float red_s[4];
    __shared__ float4 opart_s[16];

    idx_s[t] = idx[m * W + t];
    const float4 qf = ((const float4*)(q + ((size_t)b * M + m) * D))[ci];
    __syncthreads();

    const float* kb = k + (size_t)b * M * D;
    const int wbase = wave * 64;

    #pragma unroll
    for (int j = 0; j < 16; ++j) {
        const int w = wbase + j * 4 + r;
        const float4 kv = ((const float4*)(kb + (size_t)idx_s[w] * D))[ci];
        float part = kv.x * qf.x + kv.y * qf.y + kv.z * qf.z + kv.w * qf.w;
        part += __shfl_xor(part, 1);
        part += __shfl_xor(part, 2);
        part += __shfl_xor(part, 4);
        part += __shfl_xor(part, 8);
        if (ci == 0) sc_s[w] = part;
    }
    __syncthreads();

    float logit = sc_s[t];
    float mx = logit;
    #pragma unroll
    for (int o = 1; o < 64; o <<= 1) mx = fmaxf(mx, __shfl_xor(mx, o));
    if (lane == 0) red_s[wave] = mx;
    __syncthreads();
    mx = fmaxf(red_s[0], red_s[1]);
    float e = __expf(logit - mx);
    float sm = e;
    #pragma unroll
    for (int o = 1; o < 64; o <<= 1) sm += __shfl_xor(sm, o);
    if (lane == 0) red_s[2 + wave] = sm;
    __syncthreads();
    const float inv_denom = 1.0f / (red_s[2] + red_s[3]);
    sc_s[t] = e * inv_denom;
    __syncthreads();

    const float* vb = v + (size_t)b * M * D;
    float4 acc = {0.f, 0.f, 0.f, 0.f};
    #pragma unroll
    for (int j = 0; j < 16; ++j) {
        const int w = wbase + j * 4 + r;
        const float p = sc_s[w];
        const float4 vv = ((const float4*)(vb + (size_t)idx_s[w] * D))[ci];
        acc.x += p * vv.x; acc.y += p * vv.y;
        acc.z += p * vv.z; acc.w += p * vv.w;
    }
    acc.x += __shfl_xor(acc.x, 16); acc.y += __shfl_xor(acc.y, 16);
    acc.z += __shfl_xor(acc.z, 16); acc.w += __shfl_xor(acc.w, 16);
    acc.x += __shfl_xor(acc.x, 32); acc.y += __shfl_xor(acc.y, 32);
    acc.z += __shfl_xor(acc.z, 32); acc.w += __shfl_xor(acc.w, 32);

    if (wave == 0 && r == 0) opart_s[ci] = acc;
    __syncthreads();
    if (wave == 1 && r == 0) {
        const float4 o0 = opart_s[ci];
        float4 res;
        res.x = o0.x + acc.x; res.y = o0.y + acc.y;
        res.z = o0.z + acc.z; res.w = o0.w + acc.w;
        ((float4*)(out + ((size_t)b * M + m) * D))[ci] = res;
    }
}

extern "C" void kernel_launch(void* const* d_in, const int* in_sizes, int n_in,
                              void* d_out, int out_size, void* d_ws, size_t ws_size,
                              hipStream_t stream) {
    const float* q = (const float*)d_in[0];
    const float* k = (const float*)d_in[1];
    const float* v = (const float*)d_in[2];
    const int* idx = (const int*)d_in[3];
    float* out = (float*)d_out;

    // workspace: kh (2 MB) | vh (2 MB) | idx2t u16 transposed (1 MB)
    const size_t sz_kv   = (size_t)NELEM * sizeof(__half);
    const size_t sz_idx2 = (size_t)M * W * sizeof(unsigned short);
    const size_t need = 2 * sz_kv + sz_idx2;
    if (ws_size >= need) {
        __half* khp = (__half*)d_ws;
        __half* vhp = khp + NELEM;
        unsigned short* idx2t = (unsigned short*)((char*)d_ws + 2 * sz_kv);

        const int n4 = NELEM / 4;
        const int cblk = (2 * n4 + 255) / 256;
        cvt_f32_f16_2<<<cblk, 256, 0, stream>>>((const float4*)k, (const float4*)v,
                                                (__half2*)khp, (__half2*)vhp, n4);
        bucket_idx_t<<<M / 4, 256, 0, stream>>>(idx, idx2t);
        sparse_attn_p2<<<B * M / RB, 512, 0, stream>>>(q, khp, vhp, idx2t, out);
    } else {
        sparse_attn_f32<<<B * M, 128, 0, stream>>>(q, k, v, idx, out);
    }
}

// Round 12
// 93.390 us; speedup vs baseline: 1.6541x; 1.6541x over previous
//
#include <hip/hip_runtime.h>
#include <hip/hip_fp16.h>
#include <math.h>

// Problem constants: B=4, M=4096, D=64, W=128
constexpr int B = 4;
constexpr int M = 4096;
constexpr int D = 64;
constexpr int W = 128;
constexpr int NELEM = B * M * D;   // 1,048,576 per tensor

typedef _Float16 h2_t __attribute__((ext_vector_type(2)));
typedef int      i4_t __attribute__((ext_vector_type(4)));

// ---- pass 1: fp32 -> fp16 of k AND v in a single launch ----
__global__ __launch_bounds__(256) void cvt_f32_f16_2(
    const float4* __restrict__ k, const float4* __restrict__ v,
    __half2* __restrict__ kh, __half2* __restrict__ vh, int n4) {
    int i = blockIdx.x * 256 + threadIdx.x;
    const float4* src;
    __half2* dst;
    if (i < n4) { src = k; dst = kh; }
    else        { src = v; dst = vh; i -= n4; if (i >= n4) return; }
    float4 f = src[i];
    dst[2 * i]     = __floats2half2_rn(f.x, f.y);
    dst[2 * i + 1] = __floats2half2_rn(f.z, f.w);
}

// ---- main kernel: one WAVE per (b,m) row; 4 waves (4 m-rows) per block ----
// SESSION LEDGER (why this structure is final):
//  * This random-gather kernel: main ~40 µs, dur 92.7 (R1/R3).
//  * Floor analysis: 16384 rows x 256 gathered 128-B rows = 4.2M L1
//    line-fills; per-CU miss-tracking (~32 in flight / ~200 cy L2) caps
//    chip at ~0.16 lines/cy/CU => ~43 µs. Confirmed twice by zero-delta
//    experiments: NT-vs-temporal policy (R0->R1: 94.6->92.7, noise) and
//    2x memory-level-parallelism restructure (R3: 93.4, zero delta).
//  * Tiled/dense-stream alternative (R4-R11): kills the gather (FETCH
//    9 MB) but its consume machinery floors at 74-110 µs main + an extra
//    launch — strictly worse (dur 147-182). Reverted.
//  * Remaining dur budget: ~43 µs harness workspace-fill (untouchable),
//    ~2.5 µs cvt, ~40 µs main (MSHR-bound), ~5-7 µs launch gaps.
__global__ __launch_bounds__(256, 4) void sparse_attn_f16(
    const float* __restrict__ q,
    const __half* __restrict__ kh,
    const __half* __restrict__ vh,
    const int*   __restrict__ idx,
    float*       __restrict__ out)
{
    const int blk  = blockIdx.x;
    const int b    = blk & 3;              // XCD pinning -> batch L2-resident
    const int mb   = (blk >> 2) * 4;
    const int t    = threadIdx.x;
    const int wave = t >> 6;
    const int lane = t & 63;
    const int ci   = lane & 7;
    const int r    = lane >> 3;
    const int m    = mb + wave;

    __shared__ int idx_s[4 * W];

    ((int2*)idx_s)[t] = ((const int2*)(idx + (size_t)mb * W))[t];

    // q chunk for this lane (dims [ci*8, ci*8+8)) as 4x half2 for fdot2
    const float* qrow = q + ((size_t)b * M + m) * D;
    const float4 qa = ((const float4*)qrow)[2 * ci];
    const float4 qb = ((const float4*)qrow)[2 * ci + 1];
    h2_t qh[4];
    qh[0] = (h2_t){(_Float16)qa.x, (_Float16)qa.y};
    qh[1] = (h2_t){(_Float16)qa.z, (_Float16)qa.w};
    qh[2] = (h2_t){(_Float16)qb.x, (_Float16)qb.y};
    qh[3] = (h2_t){(_Float16)qb.z, (_Float16)qb.w};

    __syncthreads();   // the only barrier

    // 32-bit byte offsets into the batch's fp16 planes; reused for k and v.
    int voff[16];
    #pragma unroll
    for (int j = 0; j < 16; ++j)
        voff[j] = idx_s[wave * W + j * 8 + r] * (D * 2) + ci * 16;

    const char* kb = (const char*)(kh + (size_t)b * M * D);
    const char* vb = (const char*)(vh + (size_t)b * M * D);

    // ---- logits: 2 register batches of 8 gathers + fdot2 ----
    float larr[16];
    #pragma unroll
    for (int batch = 0; batch < 2; ++batch) {
        i4_t kreg[8];
        #pragma unroll
        for (int jj = 0; jj < 8; ++jj)
            kreg[jj] = *(const i4_t*)(kb + voff[batch * 8 + jj]);
        #pragma unroll
        for (int jj = 0; jj < 8; ++jj) {
            union { i4_t v; h2_t h[4]; } u;
            u.v = kreg[jj];
            float part = 0.f;
            part = __builtin_amdgcn_fdot2(u.h[0], qh[0], part, false);
            part = __builtin_amdgcn_fdot2(u.h[1], qh[1], part, false);
            part = __builtin_amdgcn_fdot2(u.h[2], qh[2], part, false);
            part = __builtin_amdgcn_fdot2(u.h[3], qh[3], part, false);
            part += __shfl_xor(part, 1);
            part += __shfl_xor(part, 2);
            part += __shfl_xor(part, 4);
            larr[batch * 8 + jj] = part;   // logit for w = (batch*8+jj)*8 + r
        }
    }

    // ---- issue first v batch; the softmax chain below hides its latency ----
    i4_t vreg0[8];
    #pragma unroll
    for (int jj = 0; jj < 8; ++jj)
        vreg0[jj] = *(const i4_t*)(vb + voff[jj]);

    // ---- softmax, fully in-register ----
    float mx = larr[0];
    #pragma unroll
    for (int j = 1; j < 16; ++j) mx = fmaxf(mx, larr[j]);
    mx = fmaxf(mx, __shfl_xor(mx, 8));
    mx = fmaxf(mx, __shfl_xor(mx, 16));
    mx = fmaxf(mx, __shfl_xor(mx, 32));

    float sum = 0.f;
    #pragma unroll
    for (int j = 0; j < 16; ++j) { larr[j] = __expf(larr[j] - mx); sum += larr[j]; }
    sum += __shfl_xor(sum, 8);
    sum += __shfl_xor(sum, 16);
    sum += __shfl_xor(sum, 32);
    const float inv = 1.0f / sum;   // folded into the final store

    // ---- weighted V accumulate (batch 1 issued while batch 0 consumed) ----
    float acc[8] = {0, 0, 0, 0, 0, 0, 0, 0};
    i4_t vreg1[8];
    #pragma unroll
    for (int jj = 0; jj < 8; ++jj)
        vreg1[jj] = *(const i4_t*)(vb + voff[8 + jj]);

    #pragma unroll
    for (int jj = 0; jj < 8; ++jj) {
        const float p = larr[jj];
        union { i4_t v; h2_t h[4]; } u;
        u.v = vreg0[jj];
        #pragma unroll
        for (int c = 0; c < 4; ++c) {
            acc[2 * c]     += p * (float)u.h[c][0];
            acc[2 * c + 1] += p * (float)u.h[c][1];
        }
    }
    #pragma unroll
    for (int jj = 0; jj < 8; ++jj) {
        const float p = larr[8 + jj];
        union { i4_t v; h2_t h[4]; } u;
        u.v = vreg1[jj];
        #pragma unroll
        for (int c = 0; c < 4; ++c) {
            acc[2 * c]     += p * (float)u.h[c][0];
            acc[2 * c + 1] += p * (float)u.h[c][1];
        }
    }
    #pragma unroll
    for (int o = 8; o < 64; o <<= 1) {
        #pragma unroll
        for (int i = 0; i < 8; ++i) acc[i] += __shfl_xor(acc[i], o);
    }

    if (r == 0) {
        float4* orow = (float4*)(out + ((size_t)b * M + m) * D);
        orow[2 * ci]     = make_float4(acc[0] * inv, acc[1] * inv,
                                       acc[2] * inv, acc[3] * inv);
        orow[2 * ci + 1] = make_float4(acc[4] * inv, acc[5] * inv,
                                       acc[6] * inv, acc[7] * inv);
    }
}

// ---- fallback fp32 kernel if workspace too small ----
__global__ __launch_bounds__(128) void sparse_attn_f32(
    const float* __restrict__ q,
    const float* __restrict__ k,
    const float* __restrict__ v,
    const int*   __restrict__ idx,
    float*       __restrict__ out)
{
    const int blk = blockIdx.x;
    const int b = blk & 3;
    const int m = blk >> 2;
    const int t = threadIdx.x;
    const int lane = t & 63;
    const int wave = t >> 6;
    const int ci = lane & 15;
    const int r  = lane >> 4;

    __shared__ int   idx_s[W];
    __shared__ float sc_s[W];
    __shared__ float red_s[4];
    __shared__ float4 opart_s[16];

    idx_s[t] = idx[m * W + t];
    const float4 qf = ((const float4*)(q + ((size_t)b * M + m) * D))[ci];
    __syncthreads();

    const float* kb = k + (size_t)b * M * D;
    const int wbase = wave * 64;

    #pragma unroll
    for (int j = 0; j < 16; ++j) {
        const int w = wbase + j * 4 + r;
        const float4 kv = ((const float4*)(kb + (size_t)idx_s[w] * D))[ci];
        float part = kv.x * qf.x + kv.y * qf.y + kv.z * qf.z + kv.w * qf.w;
        part += __shfl_xor(part, 1);
        part += __shfl_xor(part, 2);
        part += __shfl_xor(part, 4);
        part += __shfl_xor(part, 8);
        if (ci == 0) sc_s[w] = part;
    }
    __syncthreads();

    float logit = sc_s[t];
    float mx = logit;
    #pragma unroll
    for (int o = 1; o < 64; o <<= 1) mx = fmaxf(mx, __shfl_xor(mx, o));
    if (lane == 0) red_s[wave] = mx;
    __syncthreads();
    mx = fmaxf(red_s[0], red_s[1]);
    float e = __expf(logit - mx);
    float sm = e;
    #pragma unroll
    for (int o = 1; o < 64; o <<= 1) sm += __shfl_xor(sm, o);
    if (lane == 0) red_s[2 + wave] = sm;
    __syncthreads();
    const float inv_denom = 1.0f / (red_s[2] + red_s[3]);
    sc_s[t] = e * inv_denom;
    __syncthreads();

    const float* vb = v + (size_t)b * M * D;
    float4 acc = {0.f, 0.f, 0.f, 0.f};
    #pragma unroll
    for (int j = 0; j < 16; ++j) {
        const int w = wbase + j * 4 + r;
        const float p = sc_s[w];
        const float4 vv = ((const float4*)(vb + (size_t)idx_s[w] * D))[ci];
        acc.x += p * vv.x; acc.y += p * vv.y;
        acc.z += p * vv.z; acc.w += p * vv.w;
    }
    acc.x += __shfl_xor(acc.x, 16); acc.y += __shfl_xor(acc.y, 16);
    acc.z += __shfl_xor(acc.z, 16); acc.w += __shfl_xor(acc.w, 16);
    acc.x += __shfl_xor(acc.x, 32); acc.y += __shfl_xor(acc.y, 32);
    acc.z += __shfl_xor(acc.z, 32); acc.w += __shfl_xor(acc.w, 32);

    if (wave == 0 && r == 0) opart_s[ci] = acc;
    __syncthreads();
    if (wave == 1 && r == 0) {
        const float4 o0 = opart_s[ci];
        float4 res;
        res.x = o0.x + acc.x; res.y = o0.y + acc.y;
        res.z = o0.z + acc.z; res.w = o0.w + acc.w;
        ((float4*)(out + ((size_t)b * M + m) * D))[ci] = res;
    }
}

extern "C" void kernel_launch(void* const* d_in, const int* in_sizes, int n_in,
                              void* d_out, int out_size, void* d_ws, size_t ws_size,
                              hipStream_t stream) {
    const float* q = (const float*)d_in[0];
    const float* k = (const float*)d_in[1];
    const float* v = (const float*)d_in[2];
    const int* idx = (const int*)d_in[3];
    float* out = (float*)d_out;

    const size_t need = (size_t)2 * NELEM * sizeof(__half);  // 4 MiB
    if (ws_size >= need) {
        __half* kh = (__half*)d_ws;
        __half* vh = kh + NELEM;
        const int n4 = NELEM / 4;
        const int cblk = (2 * n4 + 255) / 256;
        cvt_f32_f16_2<<<cblk, 256, 0, stream>>>((const float4*)k, (const float4*)v,
                                                (__half2*)kh, (__half2*)vh, n4);
        sparse_attn_f16<<<B * M / 4, 256, 0, stream>>>(q, kh, vh, idx, out);
    } else {
        sparse_attn_f32<<<B * M, 128, 0, stream>>>(q, k, v, idx, out);
    }
}